// Round 10
// baseline (824.801 us; speedup 1.0000x reference)
//
#include <hip/hip_runtime.h>

typedef __attribute__((ext_vector_type(8))) short short8v;   // 8 bf16 (4 VGPRs)
typedef __attribute__((ext_vector_type(4))) float f32x4;
typedef __attribute__((ext_vector_type(16))) float f32x16;

#define HID 4096
#define SEQL 2048
#define NH 32
#define HD 128
#define MROWS 4096  // BATCH*SEQ

// ---- helpers -------------------------------------------------------------

__device__ __forceinline__ void gl_lds16(const void* g, void* l) {
  // async global->LDS, 16B per lane; LDS dest = wave-uniform base + lane*16
  __builtin_amdgcn_global_load_lds(
      (const __attribute__((address_space(1))) unsigned int*)g,
      (__attribute__((address_space(3))) unsigned int*)l, 16, 0, 0);
}

__device__ __forceinline__ unsigned short f2bf(float x) {
  union { float f; unsigned u; } v; v.f = x;
  return (unsigned short)((v.u + 0x7FFFu + ((v.u >> 16) & 1u)) >> 16);
}

#define BAR()    __builtin_amdgcn_s_barrier()
#define LGKM0()  asm volatile("s_waitcnt lgkmcnt(0)" ::: "memory")
#define VM0()    asm volatile("s_waitcnt vmcnt(0)" ::: "memory")
#define VM2()    asm volatile("s_waitcnt vmcnt(2)" ::: "memory")
#define VM4()    asm volatile("s_waitcnt vmcnt(4)" ::: "memory")
#define SCHED0() __builtin_amdgcn_sched_barrier(0)

// ---- fp32 -> bf16 cast (X, Wq, Wk, Wv) -----------------------------------

__global__ __launch_bounds__(256) void cast_bf16_kernel(
    const float* __restrict__ s0, const float* __restrict__ s1,
    const float* __restrict__ s2, const float* __restrict__ s3,
    unsigned short* __restrict__ dst)
{
  const float* src = blockIdx.y == 0 ? s0 : blockIdx.y == 1 ? s1
                   : blockIdx.y == 2 ? s2 : s3;
  unsigned short* d = dst + (size_t)blockIdx.y * ((size_t)HID * MROWS);
  size_t i = (size_t)blockIdx.x * blockDim.x + threadIdx.x;  // 8 elems/thread
  const float4* s4 = (const float4*)src;
  float4 a = s4[2 * i], b = s4[2 * i + 1];
  short8v o;
  o[0] = (short)f2bf(a.x); o[1] = (short)f2bf(a.y);
  o[2] = (short)f2bf(a.z); o[3] = (short)f2bf(a.w);
  o[4] = (short)f2bf(b.x); o[5] = (short)f2bf(b.y);
  o[6] = (short)f2bf(b.z); o[7] = (short)f2bf(b.w);
  *(short8v*)(d + i * 8) = o;
}

// ---- fused QKV GEMM: 8-phase 256x256 tile, BK=64, 8 waves (2Mx4N) --------
// R10: R8's schedule (stages, vmcnt(4)@ph3/ph7, LGKM0-per-phase) with MFMA
// shape 32x32x16 (8 MFMA/phase vs 16): +15% pipe rate (2382 vs 2075 TF
// ubench), half the MFMA issue slots. Fragment mappings = the attn kernel's
// proven 32x32 layouts. Reads regrouped by kk-slice, same 24 b128/K-tile,
// same read-end deadlines: B dbuf reads end ph1 (stage@ph2), A end ph2
// (stage@ph3); VM4@ph7 retires ph2..ph5 stages before next ph0.
__global__ __launch_bounds__(512, 2) void gemm_qkv_kernel(
    const unsigned short* __restrict__ A,
    const unsigned short* __restrict__ Wq,
    const unsigned short* __restrict__ Wk,
    const unsigned short* __restrict__ Wv,
    unsigned short* __restrict__ Qo,
    unsigned short* __restrict__ Ko,
    unsigned short* __restrict__ Vo)
{
  __shared__ unsigned short As[2 * 256 * 64];   // 64KB [dbuf][row256][64k swz]
  __shared__ unsigned short Bs[2 * 256 * 64];   // 64KB
  const int bid = blockIdx.x;
  const int swz = (bid & 7) * 96 + (bid >> 3);  // XCD r owns 96 consecutive
  const int which = swz >> 8;                   // uniform within block
  const int id = swz & 255;
  const unsigned short* W = which == 0 ? Wq : which == 1 ? Wk : Wv;
  unsigned short* C = which == 0 ? Qo : which == 1 ? Ko : Vo;

  const int t = threadIdx.x;
  const int lane = t & 63;
  const int l31 = lane & 31, g = lane >> 5;
  const int w = t >> 6;                 // 0..7
  const int wr = w >> 2, wc = w & 3;    // 2 x 4 wave grid
  const int bm = (id >> 4) << 8;
  const int bn = (id & 15) << 8;

  const int srow = t >> 3;              // 0..63
  const int sslot = t & 7;
  const int scol = (sslot ^ (srow & 7)) << 3;     // pre-swizzled global col
  const size_t arow0 = (size_t)(bm + srow) * HID;
  const size_t brow0 = (size_t)(bn + srow) * HID;
  const int ldsoff = (t & ~63) << 4;    // w*1024, wave-uniform

#define STAGE(isB, tile, half) do {                                          \
    int _k = ((tile) & 63) << 6;                                             \
    const unsigned short* _s = (isB) ? W : A;                                \
    size_t _r = ((isB) ? brow0 : arow0) + (size_t)(half) * 128 * HID;        \
    char* _d = (char*)((isB) ? Bs : As) + ((tile) & 1) * 32768 +             \
               (half) * 16384 + ldsoff;                                      \
    gl_lds16(&_s[_r + _k + scol], _d);                                       \
    gl_lds16(&_s[_r + (size_t)64 * HID + _k + scol], _d + 8192);             \
  } while (0)

  short8v av[4][2];   // [m][kk-pair slot]: even kk in [0], odd in [1]
  short8v bv[4][2];   // [kk][n]
  f32x16 acc[4][2] = {};

  // A-frag (32x32x16): row = wr*128 + m*32 + l31, k-chunk = kk*2 + g
#define RD_A(d, kb)                                                           \
  _Pragma("unroll") for (int mm = 0; mm < 4; ++mm) {                          \
    int row = wr * 128 + mm * 32 + l31;                                      \
    av[mm][0] = *(const short8v*)&As[(d)*16384 + row*64 + ((((kb)*2   + g)) ^ (row&7))*8]; \
    av[mm][1] = *(const short8v*)&As[(d)*16384 + row*64 + ((((kb)*2+2 + g)) ^ (row&7))*8]; \
  }
  // B-frag: row (N) = wc*64 + n*32 + l31, k-chunk = kk*2 + g
#define RD_B2(d, kk)                                                          \
  _Pragma("unroll") for (int nn = 0; nn < 2; ++nn) {                          \
    int row = wc * 64 + nn * 32 + l31;                                       \
    bv[kk][nn] = *(const short8v*)&Bs[(d)*16384 + row*64 + (((kk)*2 + g) ^ (row&7))*8]; \
  }
#define MFMA8(kk, sel)                                                        \
  __builtin_amdgcn_s_setprio(1);                                              \
  _Pragma("unroll") for (int mm = 0; mm < 4; ++mm)                            \
  _Pragma("unroll") for (int nn = 0; nn < 2; ++nn)                            \
    acc[mm][nn] = __builtin_amdgcn_mfma_f32_32x32x16_bf16(                    \
        av[mm][sel], bv[kk][nn], acc[mm][nn], 0, 0, 0);                       \
  __builtin_amdgcn_s_setprio(0);

  STAGE(1, 0, 0); STAGE(1, 0, 1); STAGE(0, 0, 0); STAGE(0, 0, 1);
  STAGE(1, 1, 0); STAGE(1, 1, 1);
  VM4(); BAR(); SCHED0();

  for (int i = 0; i < 32; ++i) {
    int j = 2 * i;
    // ph0: A kk0,kk1 (8 rd) + B kk0,kk1 (4 rd)
    RD_A(0, 0); RD_B2(0, 0); RD_B2(0, 1); STAGE(0, j + 1, 0);
    BAR(); LGKM0(); SCHED0(); MFMA8(0, 0); BAR(); SCHED0();
    // ph1: B kk2,kk3 (4 rd) -- B dbuf0 reads done
    RD_B2(0, 2); RD_B2(0, 3); STAGE(0, j + 1, 1);
    BAR(); LGKM0(); SCHED0(); MFMA8(1, 1); BAR(); SCHED0();
    // ph2: A kk2,kk3 (8 rd) -- A dbuf0 reads done
    RD_A(0, 2); STAGE(1, j + 2, 0);
    BAR(); LGKM0(); SCHED0(); MFMA8(2, 0); BAR(); SCHED0();
    // ph3
    STAGE(0, j + 2, 0); VM4();
    BAR(); MFMA8(3, 1); BAR(); SCHED0();
    // ph4
    RD_A(1, 0); RD_B2(1, 0); RD_B2(1, 1); STAGE(1, j + 2, 1);
    BAR(); LGKM0(); SCHED0(); MFMA8(0, 0); BAR(); SCHED0();
    // ph5
    RD_B2(1, 2); RD_B2(1, 3); STAGE(0, j + 2, 1);
    BAR(); LGKM0(); SCHED0(); MFMA8(1, 1); BAR(); SCHED0();
    // ph6
    RD_A(1, 2); STAGE(1, j + 3, 0);
    BAR(); LGKM0(); SCHED0(); MFMA8(2, 0); BAR(); SCHED0();
    // ph7
    STAGE(1, j + 3, 1); VM4();
    BAR(); MFMA8(3, 1); BAR(); SCHED0();
  }

  // epilogue: 32x32 C/D layout: col = lane&31, row = (r&3)+8*(r>>2)+4*g
#pragma unroll
  for (int m = 0; m < 4; ++m) {
#pragma unroll
    for (int n = 0; n < 2; ++n) {
      int col = bn + wc * 64 + n * 32 + l31;
      int rbase = bm + wr * 128 + m * 32 + g * 4;
      if (which < 2) {
#pragma unroll
        for (int r = 0; r < 16; ++r) {
          int row = rbase + (r & 3) + ((r >> 2) << 3);
          C[(size_t)row * HID + col] = f2bf(acc[m][n][r]);
        }
      } else {   // V: scatter to Vt[b*32+h][d][s], 4 consecutive s per group
        int head = col >> 7, dd = col & 127;
#pragma unroll
        for (int rr = 0; rr < 4; ++rr) {
          int row = rbase + rr * 8;
          int bb = row >> 11, s = row & 2047;
          unsigned short* p = C + ((size_t)(bb * NH + head) * HD + dd) * (size_t)SEQL + s;
          union { unsigned short us[4]; uint2 v; } pk;
          pk.us[0] = f2bf(acc[m][n][rr * 4 + 0]);
          pk.us[1] = f2bf(acc[m][n][rr * 4 + 1]);
          pk.us[2] = f2bf(acc[m][n][rr * 4 + 2]);
          pk.us[3] = f2bf(acc[m][n][rr * 4 + 3]);
          *(uint2*)p = pk.v;
        }
      }
    }
  }
#undef STAGE
#undef RD_A
#undef RD_B2
#undef MFMA8
}

// ---- attention: two-pass exact softmax + PV ------------------------------
// (unchanged from R8: 8 waves, QBLK=256, K/V triple-buffered, counted vmcnt,
// setprio, NT stores, exp2-folded softmax, XCD swizzle.)
__global__ __launch_bounds__(512, 2) void attn_kernel(
    const unsigned short* __restrict__ Q,   // [4096][4096] bf16
    const unsigned short* __restrict__ K,   // [4096][4096] bf16
    const unsigned short* __restrict__ Vt,  // [64][128][2048] bf16
    float* __restrict__ attn_out,           // [64][2048][2048] fp32
    float* __restrict__ out)                // [2][2048][4096] fp32
{
  const int flat = blockIdx.x;
  const int sw = (flat & 7) * 64 + (flat >> 3);   // bijective, 512 blocks
  const int bh = sw >> 3;
  const int q0 = (sw & 7) << 8;
  const int b = bh >> 5, h = bh & 31;
  const int t = threadIdx.x, lane = t & 63, w = t >> 6;   // w = 0..7
  const int l31 = lane & 31, g = lane >> 5;
  const float a = 0.08838834764831845f * 1.4426950408889634f;  // scale*log2e

  __shared__ unsigned short Ks[3 * 64 * 128];   // 48KB [buf][kv][d] swz16
  __shared__ unsigned short Vs[3 * 128 * 64];   // 48KB [buf][d][kv] swz8
  __shared__ unsigned short Ps[8][32 * 64];     // 32KB per-wave, swz8

  short8v qf[8];
  {
    const unsigned short* qrow =
        Q + (size_t)(b * SEQL + q0 + w * 32 + l31) * HID + h * HD + g * 8;
#pragma unroll
    for (int c = 0; c < 8; ++c) qf[c] = *(const short8v*)(qrow + c * 16);
  }

  const int kc = (w << 6) + lane;                 // chunk id 0..511
  const int krow0 = kc >> 4, kslot = kc & 15;     // rows 0..31
  const int vrow0 = kc >> 3, vslot = kc & 7;      // rows 0..63
  const unsigned short* Ksrc =
      K + (size_t)(b * SEQL + krow0) * HID + h * HD + ((kslot ^ (krow0 & 15)) << 3);
  const unsigned short* Vsrc =
      Vt + ((size_t)bh * HD + vrow0) * (size_t)SEQL + ((vslot ^ (vrow0 & 7)) << 3);
  const int ldsw = w << 10;                       // wave-uniform byte offset

#define STAGE_K(tile, buf) do {                                              \
    const unsigned short* _k = Ksrc + (size_t)((tile) * 64) * HID;           \
    char* _d = (char*)Ks + (buf) * 16384 + ldsw;                             \
    gl_lds16(_k, _d);                                                        \
    gl_lds16(_k + (size_t)32 * HID, _d + 8192);                              \
  } while (0)
#define STAGE_V(tile, buf) do {                                              \
    const unsigned short* _v = Vsrc + (tile) * 64;                           \
    char* _d = (char*)Vs + (buf) * 16384 + ldsw;                             \
    gl_lds16(_v, _d);                                                        \
    gl_lds16(_v + (size_t)64 * SEQL, _d + 8192);                             \
  } while (0)

  float lsum[16];
#pragma unroll
  for (int r = 0; r < 16; ++r) lsum[r] = 0.f;

  // ---------------- pass 1: denominator -----------------------------------
  STAGE_K(0, 0); STAGE_K(1, 1);
  VM2(); BAR();
  for (int i = 0; i < 32; ++i) {
    if (i < 30) STAGE_K(i + 2, (i + 2) % 3);
    const unsigned short* Kc = Ks + (i % 3) * 8192;
    f32x16 s0 = {}, s1 = {};
    __builtin_amdgcn_s_setprio(1);
#pragma unroll
    for (int c = 0; c < 8; ++c) {
      int r0 = l31;
      short8v k0v = *(const short8v*)&Kc[r0 * 128 + (((c * 2 + g) ^ (r0 & 15)) * 8)];
      int r1 = 32 + l31;
      short8v k1v = *(const short8v*)&Kc[r1 * 128 + (((c * 2 + g) ^ (r1 & 15)) * 8)];
      s0 = __builtin_amdgcn_mfma_f32_32x32x16_bf16(qf[c], k0v, s0, 0, 0, 0);
      s1 = __builtin_amdgcn_mfma_f32_32x32x16_bf16(qf[c], k1v, s1, 0, 0, 0);
    }
    __builtin_amdgcn_s_setprio(0);
#pragma unroll
    for (int r = 0; r < 16; ++r)
      lsum[r] += exp2f(s0[r] * a) + exp2f(s1[r] * a);
    if (i < 30) { VM2(); } else if (i == 30) { VM0(); }
    BAR();
  }

  float lb[16];
#pragma unroll
  for (int r = 0; r < 16; ++r) {
    float e = lsum[r];
#pragma unroll
    for (int d = 1; d < 32; d <<= 1) e += __shfl_xor(e, d);
    lb[r] = -__log2f(e);
  }

  // ---------------- pass 2: write P, accumulate O = P@V --------------------
  f32x16 o[4] = {};
  float* abase = attn_out + ((size_t)bh * SEQL + q0 + w * 32) * (size_t)SEQL + l31;

  STAGE_K(0, 0); STAGE_V(0, 0); STAGE_K(1, 1); STAGE_V(1, 1);
  VM4(); BAR();
  for (int i = 0; i < 32; ++i) {
    if (i < 30) { STAGE_K(i + 2, (i + 2) % 3); STAGE_V(i + 2, (i + 2) % 3); }
    const unsigned short* Kc = Ks + (i % 3) * 8192;
    const unsigned short* Vc = Vs + (i % 3) * 8192;
    const int kt = i * 64;
    f32x16 s0 = {}, s1 = {};
    __builtin_amdgcn_s_setprio(1);
#pragma unroll
    for (int c = 0; c < 8; ++c) {
      int r0 = l31;
      short8v k0v = *(const short8v*)&Kc[r0 * 128 + (((c * 2 + g) ^ (r0 & 15)) * 8)];
      int r1 = 32 + l31;
      short8v k1v = *(const short8v*)&Kc[r1 * 128 + (((c * 2 + g) ^ (r1 & 15)) * 8)];
      s0 = __builtin_amdgcn_mfma_f32_32x32x16_bf16(qf[c], k0v, s0, 0, 0, 0);
      s1 = __builtin_amdgcn_mfma_f32_32x32x16_bf16(qf[c], k1v, s1, 0, 0, 0);
    }
    __builtin_amdgcn_s_setprio(0);
#pragma unroll
    for (int r = 0; r < 16; ++r) {
      int qr = (r & 3) + ((r >> 2) << 3) + g * 4;  // C/D row mapping 32x32
      float p0 = exp2f(__builtin_fmaf(s0[r], a, lb[r]));
      float p1 = exp2f(__builtin_fmaf(s1[r], a, lb[r]));
      __builtin_nontemporal_store(p0, &abase[(size_t)qr * SEQL + kt]);
      __builtin_nontemporal_store(p1, &abase[(size_t)qr * SEQL + kt + 32]);
      int sl0 = ((l31 >> 3)) ^ (qr & 7);
      int sl1 = (4 + (l31 >> 3)) ^ (qr & 7);
      Ps[w][qr * 64 + sl0 * 8 + (l31 & 7)] = f2bf(p0);
      Ps[w][qr * 64 + sl1 * 8 + (l31 & 7)] = f2bf(p1);
    }
    __builtin_amdgcn_s_setprio(1);
#pragma unroll
    for (int c2 = 0; c2 < 4; ++c2) {
      short8v pa = *(const short8v*)&Ps[w][l31 * 64 + (((c2 * 2 + g) ^ (l31 & 7)) * 8)];
#pragma unroll
      for (int n = 0; n < 4; ++n) {
        int vrow = n * 32 + l31;
        short8v vb = *(const short8v*)&Vc[vrow * 64 + (((c2 * 2 + g) ^ (vrow & 7)) * 8)];
        o[n] = __builtin_amdgcn_mfma_f32_32x32x16_bf16(pa, vb, o[n], 0, 0, 0);
      }
    }
    __builtin_amdgcn_s_setprio(0);
    if (i < 30) { VM4(); } else if (i == 30) { VM0(); }
    BAR();
  }

  // epilogue: out[b][s][h*128 + d], NT (never re-read)
  float* obase = out + (size_t)(b * SEQL + q0 + w * 32) * HID + h * HD + l31;
#pragma unroll
  for (int n = 0; n < 4; ++n)
#pragma unroll
    for (int r = 0; r < 16; ++r) {
      int qr = (r & 3) + ((r >> 2) << 3) + g * 4;
      __builtin_nontemporal_store(o[n][r], &obase[(size_t)qr * HID + n * 32]);
    }
#undef STAGE_K
#undef STAGE_V
}

// ---- launch --------------------------------------------------------------

extern "C" void kernel_launch(void* const* d_in, const int* in_sizes, int n_in,
                              void* d_out, int out_size, void* d_ws, size_t ws_size,
                              hipStream_t stream) {
  const float* X  = (const float*)d_in[0];
  const float* wq = (const float*)d_in[1];
  const float* wk = (const float*)d_in[2];
  const float* wv = (const float*)d_in[3];

  const size_t NEL = (size_t)HID * MROWS;  // 16777216
  unsigned short* ws  = (unsigned short*)d_ws;
  unsigned short* Xb  = ws;            // bf16 X
  unsigned short* Wqb = ws + NEL;
  unsigned short* Wkb = ws + 2 * NEL;
  unsigned short* Wvb = ws + 3 * NEL;
  unsigned short* Qb  = ws + 4 * NEL;  // bf16 Q [4096][4096]
  unsigned short* Kb  = ws + 5 * NEL;  // bf16 K [4096][4096]
  unsigned short* Vtb = ws + 6 * NEL;  // bf16 V^T per head [64][128][2048]

  float* outp  = (float*)d_out;
  float* attnp = outp + NEL;

  cast_bf16_kernel<<<dim3(8192, 4), 256, 0, stream>>>(X, wq, wk, wv, Xb);
  gemm_qkv_kernel<<<768, 512, 0, stream>>>(Xb, Wqb, Wkb, Wvb, Qb, Kb, Vtb);
  attn_kernel<<<512, 512, 0, stream>>>(Qb, Kb, Vtb, attnp, outp);
}

// Round 11
// 785.659 us; speedup vs baseline: 1.0498x; 1.0498x over previous
//
#include <hip/hip_runtime.h>

typedef __attribute__((ext_vector_type(8))) short short8v;   // 8 bf16 (4 VGPRs)
typedef __attribute__((ext_vector_type(4))) float f32x4;
typedef __attribute__((ext_vector_type(16))) float f32x16;

#define HID 4096
#define SEQL 2048
#define NH 32
#define HD 128
#define MROWS 4096  // BATCH*SEQ

// ---- helpers -------------------------------------------------------------

__device__ __forceinline__ void gl_lds16(const void* g, void* l) {
  // async global->LDS, 16B per lane; LDS dest = wave-uniform base + lane*16
  __builtin_amdgcn_global_load_lds(
      (const __attribute__((address_space(1))) unsigned int*)g,
      (__attribute__((address_space(3))) unsigned int*)l, 16, 0, 0);
}

__device__ __forceinline__ unsigned short f2bf(float x) {
  union { float f; unsigned u; } v; v.f = x;
  return (unsigned short)((v.u + 0x7FFFu + ((v.u >> 16) & 1u)) >> 16);
}

#define BAR()    __builtin_amdgcn_s_barrier()
#define LGKM0()  asm volatile("s_waitcnt lgkmcnt(0)" ::: "memory")
#define VM0()    asm volatile("s_waitcnt vmcnt(0)" ::: "memory")
#define VM2()    asm volatile("s_waitcnt vmcnt(2)" ::: "memory")
#define VM4()    asm volatile("s_waitcnt vmcnt(4)" ::: "memory")
#define SCHED0() __builtin_amdgcn_sched_barrier(0)

// ---- fp32 -> bf16 cast (X, Wq, Wk, Wv) -----------------------------------

__global__ __launch_bounds__(256) void cast_bf16_kernel(
    const float* __restrict__ s0, const float* __restrict__ s1,
    const float* __restrict__ s2, const float* __restrict__ s3,
    unsigned short* __restrict__ dst)
{
  const float* src = blockIdx.y == 0 ? s0 : blockIdx.y == 1 ? s1
                   : blockIdx.y == 2 ? s2 : s3;
  unsigned short* d = dst + (size_t)blockIdx.y * ((size_t)HID * MROWS);
  size_t i = (size_t)blockIdx.x * blockDim.x + threadIdx.x;  // 8 elems/thread
  const float4* s4 = (const float4*)src;
  float4 a = s4[2 * i], b = s4[2 * i + 1];
  short8v o;
  o[0] = (short)f2bf(a.x); o[1] = (short)f2bf(a.y);
  o[2] = (short)f2bf(a.z); o[3] = (short)f2bf(a.w);
  o[4] = (short)f2bf(b.x); o[5] = (short)f2bf(b.y);
  o[6] = (short)f2bf(b.z); o[7] = (short)f2bf(b.w);
  *(short8v*)(d + i * 8) = o;
}

// ---- fused QKV GEMM: 8-phase 256x256 tile, BK=64, 8 waves (2Mx4N) --------
// R11 = R8 exact revert (best measured: 783.7 us). R9 (counted lgkm) and
// R10 (32x32x16 MFMA) both regressed -- this schedule is the empirical
// optimum of the structure. 16x16x32 MFMA, LGKM0-per-phase, vmcnt(4) at
// ph3/ph7, stages into dead dbuf regions, XCD swizzle (96 tiles/XCD).
__global__ __launch_bounds__(512, 2) void gemm_qkv_kernel(
    const unsigned short* __restrict__ A,
    const unsigned short* __restrict__ Wq,
    const unsigned short* __restrict__ Wk,
    const unsigned short* __restrict__ Wv,
    unsigned short* __restrict__ Qo,
    unsigned short* __restrict__ Ko,
    unsigned short* __restrict__ Vo)
{
  __shared__ unsigned short As[2 * 256 * 64];   // 64KB [dbuf][row256][64k swz]
  __shared__ unsigned short Bs[2 * 256 * 64];   // 64KB
  const int bid = blockIdx.x;
  const int swz = (bid & 7) * 96 + (bid >> 3);  // XCD r owns 96 consecutive
  const int which = swz >> 8;                   // uniform within block
  const int id = swz & 255;
  const unsigned short* W = which == 0 ? Wq : which == 1 ? Wk : Wv;
  unsigned short* C = which == 0 ? Qo : which == 1 ? Ko : Vo;

  const int t = threadIdx.x;
  const int lane = t & 63;
  const int w = t >> 6;                 // 0..7
  const int wr = w >> 2, wc = w & 3;    // 2 x 4 wave grid
  const int bm = (id >> 4) << 8;
  const int bn = (id & 15) << 8;

  const int srow = t >> 3;              // 0..63
  const int sslot = t & 7;
  const int scol = (sslot ^ (srow & 7)) << 3;     // pre-swizzled global col
  const size_t arow0 = (size_t)(bm + srow) * HID;
  const size_t brow0 = (size_t)(bn + srow) * HID;
  const int ldsoff = (t & ~63) << 4;    // w*1024, wave-uniform

#define STAGE(isB, tile, half) do {                                          \
    int _k = ((tile) & 63) << 6;                                             \
    const unsigned short* _s = (isB) ? W : A;                                \
    size_t _r = ((isB) ? brow0 : arow0) + (size_t)(half) * 128 * HID;        \
    char* _d = (char*)((isB) ? Bs : As) + ((tile) & 1) * 32768 +             \
               (half) * 16384 + ldsoff;                                      \
    gl_lds16(&_s[_r + _k + scol], _d);                                       \
    gl_lds16(&_s[_r + (size_t)64 * HID + _k + scol], _d + 8192);             \
  } while (0)

  short8v av[4][2];   // 4 m-frags x kk
  short8v bv[2][4];   // kk x 4 n-frags
  f32x4 acc[8][4] = {};

#define RD_A(d, mbase)                                                        \
  _Pragma("unroll") for (int mm = 0; mm < 4; ++mm) {                          \
    int row = wr * 128 + ((mbase) + mm) * 16 + (lane & 15);                   \
    av[mm][0] = *(const short8v*)&As[(d)*16384 + row*64 + ((   (lane>>4)) ^ (row&7))*8]; \
    av[mm][1] = *(const short8v*)&As[(d)*16384 + row*64 + ((4+ (lane>>4)) ^ (row&7))*8]; \
  }
#define RD_B(d, kk)                                                           \
  _Pragma("unroll") for (int nn = 0; nn < 4; ++nn) {                          \
    int row = wc * 64 + nn * 16 + (lane & 15);                                \
    bv[kk][nn] = *(const short8v*)&Bs[(d)*16384 + row*64 + (((kk)*4 + (lane>>4)) ^ (row&7))*8]; \
  }
#define MFMA16(mbase, kk)                                                     \
  __builtin_amdgcn_s_setprio(1);                                              \
  _Pragma("unroll") for (int mm = 0; mm < 4; ++mm)                            \
  _Pragma("unroll") for (int nn = 0; nn < 4; ++nn)                            \
    acc[(mbase)+mm][nn] = __builtin_amdgcn_mfma_f32_16x16x32_bf16(            \
        av[mm][kk], bv[kk][nn], acc[(mbase)+mm][nn], 0, 0, 0);                \
  __builtin_amdgcn_s_setprio(0);

  STAGE(1, 0, 0); STAGE(1, 0, 1); STAGE(0, 0, 0); STAGE(0, 0, 1);
  STAGE(1, 1, 0); STAGE(1, 1, 1);
  VM4(); BAR(); SCHED0();

  for (int i = 0; i < 32; ++i) {
    int j = 2 * i;
    RD_A(0, 0); RD_B(0, 0); STAGE(0, j + 1, 0);
    BAR(); LGKM0(); SCHED0(); MFMA16(0, 0); BAR(); SCHED0();
    RD_B(0, 1); STAGE(0, j + 1, 1);
    BAR(); LGKM0(); SCHED0(); MFMA16(0, 1); BAR(); SCHED0();
    RD_A(0, 4); STAGE(1, j + 2, 0);
    BAR(); LGKM0(); SCHED0(); MFMA16(4, 0); BAR(); SCHED0();
    STAGE(0, j + 2, 0); VM4();
    BAR(); MFMA16(4, 1); BAR(); SCHED0();
    RD_A(1, 0); RD_B(1, 0); STAGE(1, j + 2, 1);
    BAR(); LGKM0(); SCHED0(); MFMA16(0, 0); BAR(); SCHED0();
    RD_B(1, 1); STAGE(0, j + 2, 1);
    BAR(); LGKM0(); SCHED0(); MFMA16(0, 1); BAR(); SCHED0();
    RD_A(1, 4); STAGE(1, j + 3, 0);
    BAR(); LGKM0(); SCHED0(); MFMA16(4, 0); BAR(); SCHED0();
    STAGE(1, j + 3, 1); VM4();
    BAR(); MFMA16(4, 1); BAR(); SCHED0();
  }

#pragma unroll
  for (int m = 0; m < 8; ++m) {
#pragma unroll
    for (int n = 0; n < 4; ++n) {
      int r0 = bm + wr * 128 + m * 16 + (lane >> 4) * 4;
      int col = bn + wc * 64 + n * 16 + (lane & 15);
      if (which < 2) {
#pragma unroll
        for (int j = 0; j < 4; ++j)
          C[(size_t)(r0 + j) * HID + col] = f2bf(acc[m][n][j]);
      } else {   // V: scatter to Vt[b*32+h][d][s], 4 consecutive s per lane
        int head = col >> 7, dd = col & 127;
        int bb = r0 >> 11, s = r0 & 2047;
        unsigned short* p = C + ((size_t)(bb * NH + head) * HD + dd) * (size_t)SEQL + s;
        union { unsigned short us[4]; uint2 v; } pk;
        pk.us[0] = f2bf(acc[m][n][0]); pk.us[1] = f2bf(acc[m][n][1]);
        pk.us[2] = f2bf(acc[m][n][2]); pk.us[3] = f2bf(acc[m][n][3]);
        *(uint2*)p = pk.v;
      }
    }
  }
#undef STAGE
#undef RD_A
#undef RD_B
#undef MFMA16
}

// ---- attention: two-pass exact softmax + PV ------------------------------
// (unchanged from R8: 8 waves, QBLK=256, K/V triple-buffered, counted vmcnt,
// setprio, NT stores, exp2-folded softmax, XCD swizzle.)
__global__ __launch_bounds__(512, 2) void attn_kernel(
    const unsigned short* __restrict__ Q,   // [4096][4096] bf16
    const unsigned short* __restrict__ K,   // [4096][4096] bf16
    const unsigned short* __restrict__ Vt,  // [64][128][2048] bf16
    float* __restrict__ attn_out,           // [64][2048][2048] fp32
    float* __restrict__ out)                // [2][2048][4096] fp32
{
  const int flat = blockIdx.x;
  const int sw = (flat & 7) * 64 + (flat >> 3);   // bijective, 512 blocks
  const int bh = sw >> 3;
  const int q0 = (sw & 7) << 8;
  const int b = bh >> 5, h = bh & 31;
  const int t = threadIdx.x, lane = t & 63, w = t >> 6;   // w = 0..7
  const int l31 = lane & 31, g = lane >> 5;
  const float a = 0.08838834764831845f * 1.4426950408889634f;  // scale*log2e

  __shared__ unsigned short Ks[3 * 64 * 128];   // 48KB [buf][kv][d] swz16
  __shared__ unsigned short Vs[3 * 128 * 64];   // 48KB [buf][d][kv] swz8
  __shared__ unsigned short Ps[8][32 * 64];     // 32KB per-wave, swz8

  short8v qf[8];
  {
    const unsigned short* qrow =
        Q + (size_t)(b * SEQL + q0 + w * 32 + l31) * HID + h * HD + g * 8;
#pragma unroll
    for (int c = 0; c < 8; ++c) qf[c] = *(const short8v*)(qrow + c * 16);
  }

  const int kc = (w << 6) + lane;                 // chunk id 0..511
  const int krow0 = kc >> 4, kslot = kc & 15;     // rows 0..31
  const int vrow0 = kc >> 3, vslot = kc & 7;      // rows 0..63
  const unsigned short* Ksrc =
      K + (size_t)(b * SEQL + krow0) * HID + h * HD + ((kslot ^ (krow0 & 15)) << 3);
  const unsigned short* Vsrc =
      Vt + ((size_t)bh * HD + vrow0) * (size_t)SEQL + ((vslot ^ (vrow0 & 7)) << 3);
  const int ldsw = w << 10;                       // wave-uniform byte offset

#define STAGE_K(tile, buf) do {                                              \
    const unsigned short* _k = Ksrc + (size_t)((tile) * 64) * HID;           \
    char* _d = (char*)Ks + (buf) * 16384 + ldsw;                             \
    gl_lds16(_k, _d);                                                        \
    gl_lds16(_k + (size_t)32 * HID, _d + 8192);                              \
  } while (0)
#define STAGE_V(tile, buf) do {                                              \
    const unsigned short* _v = Vsrc + (tile) * 64;                           \
    char* _d = (char*)Vs + (buf) * 16384 + ldsw;                             \
    gl_lds16(_v, _d);                                                        \
    gl_lds16(_v + (size_t)64 * SEQL, _d + 8192);                             \
  } while (0)

  float lsum[16];
#pragma unroll
  for (int r = 0; r < 16; ++r) lsum[r] = 0.f;

  // ---------------- pass 1: denominator -----------------------------------
  STAGE_K(0, 0); STAGE_K(1, 1);
  VM2(); BAR();
  for (int i = 0; i < 32; ++i) {
    if (i < 30) STAGE_K(i + 2, (i + 2) % 3);
    const unsigned short* Kc = Ks + (i % 3) * 8192;
    f32x16 s0 = {}, s1 = {};
    __builtin_amdgcn_s_setprio(1);
#pragma unroll
    for (int c = 0; c < 8; ++c) {
      int r0 = l31;
      short8v k0v = *(const short8v*)&Kc[r0 * 128 + (((c * 2 + g) ^ (r0 & 15)) * 8)];
      int r1 = 32 + l31;
      short8v k1v = *(const short8v*)&Kc[r1 * 128 + (((c * 2 + g) ^ (r1 & 15)) * 8)];
      s0 = __builtin_amdgcn_mfma_f32_32x32x16_bf16(qf[c], k0v, s0, 0, 0, 0);
      s1 = __builtin_amdgcn_mfma_f32_32x32x16_bf16(qf[c], k1v, s1, 0, 0, 0);
    }
    __builtin_amdgcn_s_setprio(0);
#pragma unroll
    for (int r = 0; r < 16; ++r)
      lsum[r] += exp2f(s0[r] * a) + exp2f(s1[r] * a);
    if (i < 30) { VM2(); } else if (i == 30) { VM0(); }
    BAR();
  }

  float lb[16];
#pragma unroll
  for (int r = 0; r < 16; ++r) {
    float e = lsum[r];
#pragma unroll
    for (int d = 1; d < 32; d <<= 1) e += __shfl_xor(e, d);
    lb[r] = -__log2f(e);
  }

  // ---------------- pass 2: write P, accumulate O = P@V --------------------
  f32x16 o[4] = {};
  float* abase = attn_out + ((size_t)bh * SEQL + q0 + w * 32) * (size_t)SEQL + l31;

  STAGE_K(0, 0); STAGE_V(0, 0); STAGE_K(1, 1); STAGE_V(1, 1);
  VM4(); BAR();
  for (int i = 0; i < 32; ++i) {
    if (i < 30) { STAGE_K(i + 2, (i + 2) % 3); STAGE_V(i + 2, (i + 2) % 3); }
    const unsigned short* Kc = Ks + (i % 3) * 8192;
    const unsigned short* Vc = Vs + (i % 3) * 8192;
    const int kt = i * 64;
    f32x16 s0 = {}, s1 = {};
    __builtin_amdgcn_s_setprio(1);
#pragma unroll
    for (int c = 0; c < 8; ++c) {
      int r0 = l31;
      short8v k0v = *(const short8v*)&Kc[r0 * 128 + (((c * 2 + g) ^ (r0 & 15)) * 8)];
      int r1 = 32 + l31;
      short8v k1v = *(const short8v*)&Kc[r1 * 128 + (((c * 2 + g) ^ (r1 & 15)) * 8)];
      s0 = __builtin_amdgcn_mfma_f32_32x32x16_bf16(qf[c], k0v, s0, 0, 0, 0);
      s1 = __builtin_amdgcn_mfma_f32_32x32x16_bf16(qf[c], k1v, s1, 0, 0, 0);
    }
    __builtin_amdgcn_s_setprio(0);
#pragma unroll
    for (int r = 0; r < 16; ++r) {
      int qr = (r & 3) + ((r >> 2) << 3) + g * 4;  // C/D row mapping 32x32
      float p0 = exp2f(__builtin_fmaf(s0[r], a, lb[r]));
      float p1 = exp2f(__builtin_fmaf(s1[r], a, lb[r]));
      __builtin_nontemporal_store(p0, &abase[(size_t)qr * SEQL + kt]);
      __builtin_nontemporal_store(p1, &abase[(size_t)qr * SEQL + kt + 32]);
      int sl0 = ((l31 >> 3)) ^ (qr & 7);
      int sl1 = (4 + (l31 >> 3)) ^ (qr & 7);
      Ps[w][qr * 64 + sl0 * 8 + (l31 & 7)] = f2bf(p0);
      Ps[w][qr * 64 + sl1 * 8 + (l31 & 7)] = f2bf(p1);
    }
    __builtin_amdgcn_s_setprio(1);
#pragma unroll
    for (int c2 = 0; c2 < 4; ++c2) {
      short8v pa = *(const short8v*)&Ps[w][l31 * 64 + (((c2 * 2 + g) ^ (l31 & 7)) * 8)];
#pragma unroll
      for (int n = 0; n < 4; ++n) {
        int vrow = n * 32 + l31;
        short8v vb = *(const short8v*)&Vc[vrow * 64 + (((c2 * 2 + g) ^ (vrow & 7)) * 8)];
        o[n] = __builtin_amdgcn_mfma_f32_32x32x16_bf16(pa, vb, o[n], 0, 0, 0);
      }
    }
    __builtin_amdgcn_s_setprio(0);
    if (i < 30) { VM4(); } else if (i == 30) { VM0(); }
    BAR();
  }

  // epilogue: out[b][s][h*128 + d], NT (never re-read)
  float* obase = out + (size_t)(b * SEQL + q0 + w * 32) * HID + h * HD + l31;
#pragma unroll
  for (int n = 0; n < 4; ++n)
#pragma unroll
    for (int r = 0; r < 16; ++r) {
      int qr = (r & 3) + ((r >> 2) << 3) + g * 4;
      __builtin_nontemporal_store(o[n][r], &obase[(size_t)qr * HID + n * 32]);
    }
#undef STAGE_K
#undef STAGE_V
}

// ---- launch --------------------------------------------------------------

extern "C" void kernel_launch(void* const* d_in, const int* in_sizes, int n_in,
                              void* d_out, int out_size, void* d_ws, size_t ws_size,
                              hipStream_t stream) {
  const float* X  = (const float*)d_in[0];
  const float* wq = (const float*)d_in[1];
  const float* wk = (const float*)d_in[2];
  const float* wv = (const float*)d_in[3];

  const size_t NEL = (size_t)HID * MROWS;  // 16777216
  unsigned short* ws  = (unsigned short*)d_ws;
  unsigned short* Xb  = ws;            // bf16 X
  unsigned short* Wqb = ws + NEL;
  unsigned short* Wkb = ws + 2 * NEL;
  unsigned short* Wvb = ws + 3 * NEL;
  unsigned short* Qb  = ws + 4 * NEL;  // bf16 Q [4096][4096]
  unsigned short* Kb  = ws + 5 * NEL;  // bf16 K [4096][4096]
  unsigned short* Vtb = ws + 6 * NEL;  // bf16 V^T per head [64][128][2048]

  float* outp  = (float*)d_out;
  float* attnp = outp + NEL;

  cast_bf16_kernel<<<dim3(8192, 4), 256, 0, stream>>>(X, wq, wk, wv, Xb);
  gemm_qkv_kernel<<<768, 512, 0, stream>>>(Xb, Wqb, Wkb, Wvb, Qb, Kb, Vtb);
  attn_kernel<<<512, 512, 0, stream>>>(Qb, Kb, Vtb, attnp, outp);
}